// Round 9
// baseline (745.881 us; speedup 1.0000x reference)
//
#include <hip/hip_runtime.h>
#include <hip/hip_bf16.h>

#define B_    4096
#define NC    32
#define DIM   64
#define INNER 128
#define HEADS 8
#define DH    16
#define DEPTH 6
#define NCONT 64
#define CATF  2048
#define KTOT  2112
#define NROW  (B_ * NC)          // 131072 token rows

typedef __attribute__((ext_vector_type(8))) short short8;
typedef __attribute__((ext_vector_type(4))) float f32x4;
typedef __attribute__((ext_vector_type(16))) float f32x16;
typedef __attribute__((ext_vector_type(4))) unsigned short u16x4;

__device__ __forceinline__ float bf2f(__hip_bfloat16 h) { return __bfloat162float(h); }
__device__ __forceinline__ unsigned short f2bu(float f) {
    __hip_bfloat16 h = __float2bfloat16(f);
    return *(unsigned short*)&h;
}

// ---------------------------------------------------------------------------
// Generic weight transpose+cast: W [D][K][N] fp32 -> WT [D][N][K] bf16
// ---------------------------------------------------------------------------
__global__ __launch_bounds__(256) void k_wT(const float* __restrict__ W,
                                            __hip_bfloat16* __restrict__ WT,
                                            int K, int N)
{
    size_t idx = (size_t)blockIdx.x * 256 + threadIdx.x;
    int kn = K * N;
    int d = (int)(idx / kn), rem = (int)(idx % kn);
    int n = rem / K, k = rem % K;
    WT[idx] = __float2bfloat16(W[(size_t)d * kn + (size_t)k * N + n]);
}

// ---------------------------------------------------------------------------
// Transformer megakernel: emb + 6 layers + Acat cast. 2 samples/block,
// 128 threads (2 waves, wave w = sample w). Zero __syncthreads (wave-private
// LDS). Residual in registers. QK^T via 32x32x16 MFMA + in-register softmax.
// Ps is UNIONED over qh/kh (per-wave 3072B region; qh/kh live in steps 1-2
// of each head, Ps in steps 5-6; single-wave LDS ops execute in order and the
// shared char-buffer cast keeps the compiler conservative about aliasing).
// LDS = 25.5 KB -> 6 blocks/CU (12 waves/CU).
// ---------------------------------------------------------------------------
__global__ __launch_bounds__(128) void k_former(
    const int* __restrict__ x_categ, const float* __restrict__ embed,
    const float* __restrict__ ln1_g, const float* __restrict__ ln1_b,
    const __hip_bfloat16* __restrict__ wqT, const __hip_bfloat16* __restrict__ woT,
    const float* __restrict__ bo,
    const float* __restrict__ ln2_g, const float* __restrict__ ln2_b,
    const __hip_bfloat16* __restrict__ w1T, const float* __restrict__ bff1,
    const __hip_bfloat16* __restrict__ w2T, const float* __restrict__ bff2,
    __hip_bfloat16* __restrict__ Acat)
{
    __shared__ __align__(16) unsigned char Ub[64 * 136 * 2];   // 17.4 KB union
    auto U  = reinterpret_cast<__hip_bfloat16(*)[136]>(Ub);    // h / os / pg
    auto Uf = reinterpret_cast<float(*)[68]>(Ub);              // embed scratch
    __shared__ __align__(16) unsigned char QKb[2][3072];       // per-wave q/k/Ps union
    __shared__ __hip_bfloat16 vth[2][16][40];                  // per-head V^T [dh][tok]

    const int tid = threadIdx.x;
    const int w = tid >> 6, lane = tid & 63;
    const int lo = lane & 15, g = lane >> 4;
    const int q32 = lane & 31, hi = lane >> 5;
    const int r0 = blockIdx.x * 64;
    const f32x4 z4 = f32x4{0.f, 0.f, 0.f, 0.f};

    // per-wave LDS views (all row strides 16B multiples: 48/48/80 B)
    auto qhw = reinterpret_cast<__hip_bfloat16(*)[24]>(QKb[w]);          // [32][24]
    auto khw = reinterpret_cast<__hip_bfloat16(*)[24]>(QKb[w] + 1536);   // [32][24]
    auto psw = reinterpret_cast<__hip_bfloat16(*)[40]>(QKb[w]);          // [32][40] union

    // residual stream in registers: (token = mt*16+g*4+rg, col = nt*16+lo)
    float xacc[2][4][4];

    // embedding gather -> Uf (wave-local), then into xacc registers
    {
        int r = w * 32 + (lane >> 1), half = lane & 1;
        int grow = r0 + r;
        int tok = x_categ[grow] + 2 + 100 * (grow & 31);
        const float4* src = (const float4*)(embed + (size_t)tok * 64 + half * 32);
#pragma unroll
        for (int q4 = 0; q4 < 8; ++q4) {
            float4 v = src[q4];
            Uf[r][half * 32 + q4 * 4 + 0] = v.x; Uf[r][half * 32 + q4 * 4 + 1] = v.y;
            Uf[r][half * 32 + q4 * 4 + 2] = v.z; Uf[r][half * 32 + q4 * 4 + 3] = v.w;
        }
    }
#pragma unroll
    for (int mt = 0; mt < 2; ++mt)
#pragma unroll
        for (int nt = 0; nt < 4; ++nt)
#pragma unroll
            for (int rg = 0; rg < 4; ++rg)
                xacc[mt][nt][rg] = Uf[w * 32 + mt * 16 + g * 4 + rg][nt * 16 + lo];

    // LayerNorm: xacc regs -> U (bf16)
    auto layernorm = [&](const float* gam, const float* bet) {
        float gv[4], bv_[4];
#pragma unroll
        for (int nt = 0; nt < 4; ++nt) { gv[nt] = gam[nt * 16 + lo]; bv_[nt] = bet[nt * 16 + lo]; }
#pragma unroll
        for (int mt = 0; mt < 2; ++mt)
#pragma unroll
            for (int rg = 0; rg < 4; ++rg) {
                float s = xacc[mt][0][rg] + xacc[mt][1][rg] + xacc[mt][2][rg] + xacc[mt][3][rg];
                float q = xacc[mt][0][rg] * xacc[mt][0][rg] + xacc[mt][1][rg] * xacc[mt][1][rg]
                        + xacc[mt][2][rg] * xacc[mt][2][rg] + xacc[mt][3][rg] * xacc[mt][3][rg];
#pragma unroll
                for (int m = 1; m < 16; m <<= 1) { s += __shfl_xor(s, m); q += __shfl_xor(q, m); }
                float mu = s * (1.f / 64.f);
                float var = q * (1.f / 64.f) - mu * mu;
                float ri = rsqrtf(var + 1e-5f);
                int token = w * 32 + mt * 16 + g * 4 + rg;
#pragma unroll
                for (int nt = 0; nt < 4; ++nt)
                    U[token][nt * 16 + lo] = __float2bfloat16((xacc[mt][nt][rg] - mu) * ri * gv[nt] + bv_[nt]);
            }
    };

#pragma unroll 1
    for (int d = 0; d < DEPTH; ++d) {
        const __hip_bfloat16* wq_d = wqT + (size_t)d * 384 * 64;
        const __hip_bfloat16* wo_d = woT + (size_t)d * 64 * 128;
        const __hip_bfloat16* w1_d = w1T + (size_t)d * 512 * 64;
        const __hip_bfloat16* w2_d = w2T + (size_t)d * 64 * 256;

        // ---- LN1 ----
        layernorm(ln1_g + d * 64, ln1_b + d * 64);

        // A-frags of h (persist across heads)
        short8 af[2][2];
#pragma unroll
        for (int mt = 0; mt < 2; ++mt)
#pragma unroll
            for (int kk = 0; kk < 2; ++kk)
                af[mt][kk] = *(const short8*)&U[w * 32 + mt * 16 + lo][kk * 32 + g * 8];

        // ---- attention, per head ----
        for (int hh = 0; hh < HEADS; ++hh) {
            // qkv for this head (N=16 per part)
            f32x4 aq[2] = {z4, z4}, ak[2] = {z4, z4}, av[2] = {z4, z4};
#pragma unroll
            for (int kk = 0; kk < 2; ++kk) {
                short8 bq  = *(const short8*)&wq_d[(size_t)(hh * 16 + lo) * 64 + kk * 32 + g * 8];
                short8 bk  = *(const short8*)&wq_d[(size_t)(128 + hh * 16 + lo) * 64 + kk * 32 + g * 8];
                short8 bv2 = *(const short8*)&wq_d[(size_t)(256 + hh * 16 + lo) * 64 + kk * 32 + g * 8];
#pragma unroll
                for (int mt = 0; mt < 2; ++mt) {
                    aq[mt] = __builtin_amdgcn_mfma_f32_16x16x32_bf16(af[mt][kk], bq,  aq[mt], 0, 0, 0);
                    ak[mt] = __builtin_amdgcn_mfma_f32_16x16x32_bf16(af[mt][kk], bk,  ak[mt], 0, 0, 0);
                    av[mt] = __builtin_amdgcn_mfma_f32_16x16x32_bf16(af[mt][kk], bv2, av[mt], 0, 0, 0);
                }
            }
            // q/k scalar stores [tok][dh]; V^T packed b64 stores [dh][tok]
#pragma unroll
            for (int mt = 0; mt < 2; ++mt) {
#pragma unroll
                for (int rg = 0; rg < 4; ++rg) {
                    int tok = mt * 16 + g * 4 + rg;
                    qhw[tok][lo] = __float2bfloat16(aq[mt][rg]);
                    khw[tok][lo] = __float2bfloat16(ak[mt][rg]);
                }
                u16x4 vv;
                vv.x = f2bu(av[mt][0]); vv.y = f2bu(av[mt][1]);
                vv.z = f2bu(av[mt][2]); vv.w = f2bu(av[mt][3]);
                *(u16x4*)&vth[w][lo][mt * 16 + g * 4] = vv;
            }
            // QK^T: one 32x32x16 MFMA, swapped operands -> S^T (col = q)
            short8 kaf = *(const short8*)&khw[q32][hi * 8];
            short8 qaf = *(const short8*)&qhw[q32][hi * 8];
            f32x16 z16{};
            f32x16 St = __builtin_amdgcn_mfma_f32_32x32x16_bf16(kaf, qaf, z16, 0, 0, 0);
            // lane holds S^T[j][q]: q = lane&31, j(r) = (r&3) + 8*(r>>2) + 4*hi
            float sv[16];
            float mx = St[0] * 0.25f;
#pragma unroll
            for (int r = 0; r < 16; ++r) { sv[r] = St[r] * 0.25f; mx = fmaxf(mx, sv[r]); }
            mx = fmaxf(mx, __shfl_xor(mx, 32));
            float den = 0.f;
#pragma unroll
            for (int r = 0; r < 16; ++r) { sv[r] = __expf(sv[r] - mx); den += sv[r]; }
            den += __shfl_xor(den, 32);
            float rs = 1.f / den;
            // P store into psw (unions over qh/kh — qaf/kaf already in regs)
#pragma unroll
            for (int grp = 0; grp < 4; ++grp) {
                u16x4 pv;
                pv.x = f2bu(sv[grp * 4 + 0] * rs); pv.y = f2bu(sv[grp * 4 + 1] * rs);
                pv.z = f2bu(sv[grp * 4 + 2] * rs); pv.w = f2bu(sv[grp * 4 + 3] * rs);
                *(u16x4*)&psw[q32][grp * 8 + hi * 4] = pv;
            }
            // PV -> os (U cols hh*16..)
            short8 bv = *(const short8*)&vth[w][lo][g * 8];
#pragma unroll
            for (int qt = 0; qt < 2; ++qt) {
                int qrow = qt * 16 + lo;
                short8 ap = *(const short8*)&psw[qrow][g * 8];
                f32x4 ov = __builtin_amdgcn_mfma_f32_16x16x32_bf16(ap, bv, z4, 0, 0, 0);
#pragma unroll
                for (int rg = 0; rg < 4; ++rg)
                    U[w * 32 + qt * 16 + g * 4 + rg][hh * 16 + lo] = __float2bfloat16(ov[rg]);
            }
        }

        // ---- proj + residual: xacc += os @ woT^T + bo ----
        {
            short8 ap2[2][4];
#pragma unroll
            for (int mt = 0; mt < 2; ++mt)
#pragma unroll
                for (int kk = 0; kk < 4; ++kk)
                    ap2[mt][kk] = *(const short8*)&U[w * 32 + mt * 16 + lo][kk * 32 + g * 8];
            f32x4 pacc[2][4];
#pragma unroll
            for (int mt = 0; mt < 2; ++mt)
#pragma unroll
                for (int nt = 0; nt < 4; ++nt) pacc[mt][nt] = z4;
#pragma unroll
            for (int kk = 0; kk < 4; ++kk)
#pragma unroll
                for (int nt = 0; nt < 4; ++nt) {
                    short8 b = *(const short8*)&wo_d[(size_t)(nt * 16 + lo) * 128 + kk * 32 + g * 8];
#pragma unroll
                    for (int mt = 0; mt < 2; ++mt)
                        pacc[mt][nt] = __builtin_amdgcn_mfma_f32_16x16x32_bf16(ap2[mt][kk], b, pacc[mt][nt], 0, 0, 0);
                }
            float bov[4];
#pragma unroll
            for (int nt = 0; nt < 4; ++nt) bov[nt] = bo[d * 64 + nt * 16 + lo];
#pragma unroll
            for (int mt = 0; mt < 2; ++mt)
#pragma unroll
                for (int nt = 0; nt < 4; ++nt)
#pragma unroll
                    for (int rg = 0; rg < 4; ++rg)
                        xacc[mt][nt][rg] += pacc[mt][nt][rg] + bov[nt];
        }

        // ---- LN2 ----
        layernorm(ln2_g + d * 64, ln2_b + d * 64);

        // ---- ff1(geglu) + ff2, chunked (64 p-cols at a time) ----
        {
            short8 af2[2][2];
#pragma unroll
            for (int mt = 0; mt < 2; ++mt)
#pragma unroll
                for (int kk = 0; kk < 2; ++kk)
                    af2[mt][kk] = *(const short8*)&U[w * 32 + mt * 16 + lo][kk * 32 + g * 8];
            f32x4 acc2[2][4];
#pragma unroll
            for (int mt = 0; mt < 2; ++mt)
#pragma unroll
                for (int nt = 0; nt < 4; ++nt) acc2[mt][nt] = z4;

            for (int c4 = 0; c4 < 4; ++c4) {
                // geglu in two nt-halves (keeps aa/agg at [2][2] for VGPR)
#pragma unroll
                for (int nh = 0; nh < 2; ++nh) {
                    f32x4 aa[2][2], agg[2][2];
#pragma unroll
                    for (int mt = 0; mt < 2; ++mt)
#pragma unroll
                        for (int nj = 0; nj < 2; ++nj) { aa[mt][nj] = z4; agg[mt][nj] = z4; }
#pragma unroll
                    for (int kk = 0; kk < 2; ++kk)
#pragma unroll
                        for (int nj = 0; nj < 2; ++nj) {
                            int nt = nh * 2 + nj;
                            short8 ba = *(const short8*)&w1_d[(size_t)(c4 * 64 + nt * 16 + lo) * 64 + kk * 32 + g * 8];
                            short8 bg = *(const short8*)&w1_d[(size_t)(256 + c4 * 64 + nt * 16 + lo) * 64 + kk * 32 + g * 8];
#pragma unroll
                            for (int mt = 0; mt < 2; ++mt) {
                                aa[mt][nj]  = __builtin_amdgcn_mfma_f32_16x16x32_bf16(af2[mt][kk], ba, aa[mt][nj], 0, 0, 0);
                                agg[mt][nj] = __builtin_amdgcn_mfma_f32_16x16x32_bf16(af2[mt][kk], bg, agg[mt][nj], 0, 0, 0);
                            }
                        }
#pragma unroll
                    for (int mt = 0; mt < 2; ++mt)
#pragma unroll
                        for (int nj = 0; nj < 2; ++nj)
#pragma unroll
                            for (int rg = 0; rg < 4; ++rg) {
                                int nt = nh * 2 + nj;
                                int col = c4 * 64 + nt * 16 + lo;
                                float a  = aa[mt][nj][rg]  + bff1[d * 512 + col];
                                float gg = agg[mt][nj][rg] + bff1[d * 512 + 256 + col];
                                // gelu(gg) ~= gg * e/(e+1), e = exp(1.595769*(gg+0.044715 gg^3))
                                float g2 = gg * gg;
                                float t  = gg * (1.f + 0.044715f * g2);
                                float e  = __expf(1.5957691216f * t);
                                float gl = gg * e * __builtin_amdgcn_rcpf(e + 1.f);
                                U[w * 32 + mt * 16 + g * 4 + rg][nt * 16 + lo] = __float2bfloat16(a * gl);
                            }
                }
                // ff2 partial: acc2 += pg @ w2T^T (K-chunk c4)
                short8 apg[2][2];
#pragma unroll
                for (int mt = 0; mt < 2; ++mt)
#pragma unroll
                    for (int kk = 0; kk < 2; ++kk)
                        apg[mt][kk] = *(const short8*)&U[w * 32 + mt * 16 + lo][kk * 32 + g * 8];
#pragma unroll
                for (int kk = 0; kk < 2; ++kk)
#pragma unroll
                    for (int nt = 0; nt < 4; ++nt) {
                        short8 bb = *(const short8*)&w2_d[(size_t)(nt * 16 + lo) * 256 + c4 * 64 + kk * 32 + g * 8];
#pragma unroll
                        for (int mt = 0; mt < 2; ++mt)
                            acc2[mt][nt] = __builtin_amdgcn_mfma_f32_16x16x32_bf16(apg[mt][kk], bb, acc2[mt][nt], 0, 0, 0);
                    }
            }
            // residual
            float b2v[4];
#pragma unroll
            for (int nt = 0; nt < 4; ++nt) b2v[nt] = bff2[d * 64 + nt * 16 + lo];
#pragma unroll
            for (int mt = 0; mt < 2; ++mt)
#pragma unroll
                for (int nt = 0; nt < 4; ++nt)
#pragma unroll
                    for (int rg = 0; rg < 4; ++rg)
                        xacc[mt][nt][rg] += acc2[mt][nt][rg] + b2v[nt];
        }
    }

    // write Acat (bf16, cols 0..2047) straight from registers
    {
        size_t base = (size_t)(blockIdx.x * 2 + w) * KTOT;
#pragma unroll
        for (int mt = 0; mt < 2; ++mt)
#pragma unroll
            for (int rg = 0; rg < 4; ++rg) {
                int token = mt * 16 + g * 4 + rg;
#pragma unroll
                for (int nt = 0; nt < 4; ++nt)
                    Acat[base + token * 64 + nt * 16 + lo] = __float2bfloat16(xacc[mt][nt][rg]);
            }
    }
}

// ---------------------------------------------------------------------------
// BatchNorm1d (batch stats), one block per feature column.
// ---------------------------------------------------------------------------
__global__ __launch_bounds__(256) void k_bn(
    const float* __restrict__ x_cont, const float* __restrict__ bn_g, const float* __restrict__ bn_b,
    float* __restrict__ normed, __hip_bfloat16* __restrict__ Acat)
{
    const int c = blockIdx.x;
    const int tid = threadIdx.x;
    float sum = 0.f, sq = 0.f;
    for (int rr = tid; rr < B_; rr += 256) { float v = x_cont[rr * NCONT + c]; sum += v; sq += v * v; }
    __shared__ float ssum[256], ssq[256];
    ssum[tid] = sum; ssq[tid] = sq;
    __syncthreads();
    for (int st = 128; st > 0; st >>= 1) {
        if (tid < st) { ssum[tid] += ssum[tid + st]; ssq[tid] += ssq[tid + st]; }
        __syncthreads();
    }
    float mu  = ssum[0] * (1.f / B_);
    float var = ssq[0] * (1.f / B_) - mu * mu;
    float ri  = rsqrtf(var + 1e-5f);
    float gg = bn_g[c], bb = bn_b[c];
    for (int rr = tid; rr < B_; rr += 256) {
        float v = (x_cont[rr * NCONT + c] - mu) * ri * gg + bb;
        normed[rr * NCONT + c] = v;
        Acat[(size_t)rr * KTOT + CATF + c] = __float2bfloat16(v);
    }
}

// ---------------------------------------------------------------------------
// g0_w [2112,2048] fp32 -> WT [2048,2112] bf16 (k-contiguous)
// ---------------------------------------------------------------------------
__global__ __launch_bounds__(256) void k_transpose(
    const float* __restrict__ W, __hip_bfloat16* __restrict__ WT)
{
    __shared__ float tile[64][65];
    const int n0 = blockIdx.x * 64, k0 = blockIdx.y * 64;
    const int tid = threadIdx.x;
    for (int e = tid; e < 64 * 16; e += 256) {
        int rr = e >> 4, c4 = e & 15;
        float4 v = *(const float4*)&W[(size_t)(k0 + rr) * CATF + n0 + c4 * 4];
        tile[rr][c4 * 4 + 0] = v.x; tile[rr][c4 * 4 + 1] = v.y;
        tile[rr][c4 * 4 + 2] = v.z; tile[rr][c4 * 4 + 3] = v.w;
    }
    __syncthreads();
    for (int e = tid; e < 64 * 32; e += 256) {
        int n = e >> 5, kp = e & 31;
        __hip_bfloat16 h0 = __float2bfloat16(tile[kp * 2 + 0][n]);
        __hip_bfloat16 h1 = __float2bfloat16(tile[kp * 2 + 1][n]);
        unsigned u = ((unsigned)(*(unsigned short*)&h1) << 16) | (unsigned)(*(unsigned short*)&h0);
        *(unsigned*)&WT[(size_t)(n0 + n) * KTOT + k0 + kp * 2] = u;
    }
}

// ---------------------------------------------------------------------------
// G = relu(Acat[4096,2112] @ g0_w + g0_b), bf16 MFMA, 128x128 tiles, BK=64
// ---------------------------------------------------------------------------
__global__ __launch_bounds__(256) void k_gemm_g0(
    const __hip_bfloat16* __restrict__ Acat, const __hip_bfloat16* __restrict__ WT,
    const float* __restrict__ g0_b, __hip_bfloat16* __restrict__ G)
{
    __shared__ __hip_bfloat16 At[128][72];
    __shared__ __hip_bfloat16 Bt[128][72];
    const int tid = threadIdx.x;
    const int m0 = blockIdx.y * 128, n0 = blockIdx.x * 128;
    const int w = tid >> 6, lane = tid & 63, g = lane >> 4;
    const int wr = w >> 1, wc = w & 1;

    f32x4 acc[4][4];
#pragma unroll
    for (int mi = 0; mi < 4; ++mi)
#pragma unroll
        for (int ni = 0; ni < 4; ++ni) acc[mi][ni] = f32x4{0.f, 0.f, 0.f, 0.f};

    const int row_a = wr * 64 + (lane & 15);
    const int row_b = wc * 64 + (lane & 15);

    for (int kt = 0; kt < KTOT / 64; ++kt) {
        const int k0 = kt * 64;
#pragma unroll
        for (int t = 0; t < 4; ++t) {
            int e = tid + t * 256; int rr = e >> 3, seg = e & 7;
            *(uint4*)&At[rr][seg * 8] = *(const uint4*)&Acat[(size_t)(m0 + rr) * KTOT + k0 + seg * 8];
        }
#pragma unroll
        for (int t = 0; t < 4; ++t) {
            int e = tid + t * 256; int rr = e >> 3, seg = e & 7;
            *(uint4*)&Bt[rr][seg * 8] = *(const uint4*)&WT[(size_t)(n0 + rr) * KTOT + k0 + seg * 8];
        }
        __syncthreads();
        short8 af[4][2], bfr[4][2];
#pragma unroll
        for (int mi = 0; mi < 4; ++mi)
#pragma unroll
            for (int kk = 0; kk < 2; ++kk)
                af[mi][kk] = *(const short8*)&At[row_a + mi * 16][kk * 32 + g * 8];
#pragma unroll
        for (int ni = 0; ni < 4; ++ni)
#pragma unroll
            for (int kk = 0; kk < 2; ++kk)
                bfr[ni][kk] = *(const short8*)&Bt[row_b + ni * 16][kk * 32 + g * 8];
#pragma unroll
        for (int kk = 0; kk < 2; ++kk)
#pragma unroll
            for (int mi = 0; mi < 4; ++mi)
#pragma unroll
                for (int ni = 0; ni < 4; ++ni)
                    acc[mi][ni] = __builtin_amdgcn_mfma_f32_16x16x32_bf16(af[mi][kk], bfr[ni][kk], acc[mi][ni], 0, 0, 0);
        __syncthreads();
    }

#pragma unroll
    for (int mi = 0; mi < 4; ++mi)
#pragma unroll
        for (int ni = 0; ni < 4; ++ni)
#pragma unroll
            for (int reg = 0; reg < 4; ++reg) {
                int row = m0 + wr * 64 + mi * 16 + (lane >> 4) * 4 + reg;
                int col = n0 + wc * 64 + ni * 16 + (lane & 15);
                float v = acc[mi][ni][reg] + g0_b[col];
                G[(size_t)row * CATF + col] = __float2bfloat16(fmaxf(v, 0.f));
            }
}

// ---------------------------------------------------------------------------
// y1 = flat_categ @ y1_w + y1_b.  MFMA, M=4096 N=64 K=2048, 128-row blocks.
// ---------------------------------------------------------------------------
__global__ __launch_bounds__(256) void k_y1v2(
    const __hip_bfloat16* __restrict__ Acat, const __hip_bfloat16* __restrict__ y1T,
    const float* __restrict__ y1_b, float* __restrict__ y1)
{
    __shared__ __hip_bfloat16 At[128][136];
    __shared__ __hip_bfloat16 Bt[64][136];
    const int tid = threadIdx.x;
    const size_t m0 = (size_t)blockIdx.x * 128;
    const int w = tid >> 6, lane = tid & 63, lo = lane & 15, g = lane >> 4;
    f32x4 acc[2][4];
#pragma unroll
    for (int mt = 0; mt < 2; ++mt)
#pragma unroll
        for (int nt = 0; nt < 4; ++nt) acc[mt][nt] = f32x4{0.f, 0.f, 0.f, 0.f};
    for (int kt = 0; kt < 16; ++kt) {
        if (kt) __syncthreads();
#pragma unroll
        for (int t = 0; t < 8; ++t) {
            int e = tid + t * 256; int row = e >> 4, seg = e & 15;
            *(uint4*)&At[row][seg * 8] = *(const uint4*)&Acat[(m0 + row) * KTOT + kt * 128 + seg * 8];
        }
#pragma unroll
        for (int t = 0; t < 4; ++t) {
            int e = tid + t * 256; int row = e >> 4, seg = e & 15;
            *(uint4*)&Bt[row][seg * 8] = *(const uint4*)&y1T[(size_t)row * 2048 + kt * 128 + seg * 8];
        }
        __syncthreads();
#pragma unroll
        for (int kk = 0; kk < 4; ++kk) {
            short8 a[2], b[4];
#pragma unroll
            for (int mt = 0; mt < 2; ++mt) a[mt] = *(const short8*)&At[w * 32 + mt * 16 + lo][kk * 32 + g * 8];
#pragma unroll
            for (int nt = 0; nt < 4; ++nt) b[nt] = *(const short8*)&Bt[nt * 16 + lo][kk * 32 + g * 8];
#pragma unroll
            for (int mt = 0; mt < 2; ++mt)
#pragma unroll
                for (int nt = 0; nt < 4; ++nt)
                    acc[mt][nt] = __builtin_amdgcn_mfma_f32_16x16x32_bf16(a[mt], b[nt], acc[mt][nt], 0, 0, 0);
        }
    }
#pragma unroll
    for (int mt = 0; mt < 2; ++mt)
#pragma unroll
        for (int nt = 0; nt < 4; ++nt)
#pragma unroll
            for (int rg = 0; rg < 4; ++rg) {
                size_t row = m0 + w * 32 + mt * 16 + g * 4 + rg;
                int col = nt * 16 + lo;
                y1[row * 64 + col] = acc[mt][nt][rg] + y1_b[col];
            }
}

// ---------------------------------------------------------------------------
// H = G * (normed @ h0_w), in-place over G. MFMA, M=4096 N=2048 K=64.
// ---------------------------------------------------------------------------
__global__ __launch_bounds__(256) void k_H2(
    const __hip_bfloat16* __restrict__ Acat, const __hip_bfloat16* __restrict__ h0T,
    __hip_bfloat16* __restrict__ G)
{
    __shared__ __hip_bfloat16 At[128][72];
    const int tid = threadIdx.x;
    const int m0 = blockIdx.y * 128, n0 = blockIdx.x * 128;
    const int w = tid >> 6, lane = tid & 63, lo = lane & 15, g = lane >> 4;
    const int wr = w >> 1, wc = w & 1;
#pragma unroll
    for (int t = 0; t < 4; ++t) {
        int e = tid + t * 256; int row = e >> 3, seg = e & 7;
        *(uint4*)&At[row][seg * 8] = *(const uint4*)&Acat[(size_t)(m0 + row) * KTOT + CATF + seg * 8];
    }
    __syncthreads();
    f32x4 acc[4][4];
#pragma unroll
    for (int mt = 0; mt < 4; ++mt)
#pragma unroll
        for (int nt = 0; nt < 4; ++nt) acc[mt][nt] = f32x4{0.f, 0.f, 0.f, 0.f};
#pragma unroll
    for (int kk = 0; kk < 2; ++kk) {
        short8 a[4], b[4];
#pragma unroll
        for (int mt = 0; mt < 4; ++mt) a[mt] = *(const short8*)&At[wr * 64 + mt * 16 + lo][kk * 32 + g * 8];
#pragma unroll
        for (int nt = 0; nt < 4; ++nt)
            b[nt] = *(const short8*)&h0T[(size_t)(n0 + wc * 64 + nt * 16 + lo) * 64 + kk * 32 + g * 8];
#pragma unroll
        for (int mt = 0; mt < 4; ++mt)
#pragma unroll
            for (int nt = 0; nt < 4; ++nt)
                acc[mt][nt] = __builtin_amdgcn_mfma_f32_16x16x32_bf16(a[mt], b[nt], acc[mt][nt], 0, 0, 0);
    }
#pragma unroll
    for (int mt = 0; mt < 4; ++mt)
#pragma unroll
        for (int nt = 0; nt < 4; ++nt)
#pragma unroll
            for (int rg = 0; rg < 4; ++rg) {
                size_t row = (size_t)m0 + wr * 64 + mt * 16 + g * 4 + rg;
                int col = n0 + wc * 64 + nt * 16 + lo;
                size_t offo = row * CATF + col;
                G[offo] = __float2bfloat16(bf2f(G[offo]) * acc[mt][nt][rg]);
            }
}

// ---------------------------------------------------------------------------
// Final: norms, alpha, c0/c1 combine, fc dot, sigmoid. One block per row.
// ---------------------------------------------------------------------------
__global__ __launch_bounds__(256) void k_final(
    const __hip_bfloat16* __restrict__ Acat, const __hip_bfloat16* __restrict__ H,
    const float* __restrict__ normed, const float* __restrict__ y1,
    const float* __restrict__ g1_w, const float* __restrict__ g1_b, const float* __restrict__ h1_w,
    const float* __restrict__ fc_w, const float* __restrict__ fc_b,
    float* __restrict__ out)
{
    const int b = blockIdx.x;
    const int tid = threadIdx.x;
    const __hip_bfloat16* xrow = Acat + (size_t)b * KTOT;
    const __hip_bfloat16* hrow = H + (size_t)b * CATF;

    __shared__ float r1[256], r2[256];
    float sx = 0.f, sh = 0.f;
    for (int n = tid; n < CATF; n += 256) {
        float xv = bf2f(xrow[n]); sx += xv * xv;
        float hv = bf2f(hrow[n]); sh += hv * hv;
    }
    r1[tid] = sx; r2[tid] = sh;
    __syncthreads();
    for (int st = 128; st > 0; st >>= 1) {
        if (tid < st) { r1[tid] += r1[tid + st]; r2[tid] += r2[tid + st]; }
        __syncthreads();
    }
    float alpha0 = fminf(fmaxf(sqrtf(r1[0]) / (sqrtf(r2[0]) + 1e-12f) * 0.2f, 0.f), 1.f);
    __syncthreads();

    float pd = 0.f;
    for (int n = tid; n < CATF; n += 256) {
        float c0 = bf2f(xrow[n]) + alpha0 * bf2f(hrow[n]);
        pd += c0 * fc_w[n];
    }
    r1[tid] = pd;
    __syncthreads();
    for (int st = 128; st > 0; st >>= 1) {
        if (tid < st) r1[tid] += r1[tid + st];
        __syncthreads();
    }
    float dot0 = r1[0];

    __shared__ float ny[128];
    __shared__ float c1dot;
    if (tid < 64) ny[tid] = normed[b * NCONT + tid];
    else if (tid < 128) ny[tid] = y1[b * NCONT + tid - 64];
    __syncthreads();

    if (tid < 64) {
        const int j = tid;
        float g = g1_b[j];
        for (int k = 0; k < 128; ++k) g += ny[k] * g1_w[k * 64 + j];
        g = fmaxf(g, 0.f);
        float hv = 0.f;
        for (int k = 0; k < 64; ++k) hv += ny[64 + k] * h1_w[k * 64 + j];
        float H1 = g * hv;
        float nj = ny[j];
        float snx = nj * nj, snh = H1 * H1;
        for (int m = 1; m < 64; m <<= 1) { snx += __shfl_xor(snx, m, 64); snh += __shfl_xor(snh, m, 64); }
        float a1 = fminf(fmaxf(sqrtf(snx) / (sqrtf(snh) + 1e-12f) * 0.2f, 0.f), 1.f);
        float d1 = (nj + a1 * H1) * fc_w[CATF + j];
        for (int m = 1; m < 64; m <<= 1) d1 += __shfl_xor(d1, m, 64);
        if (tid == 0) c1dot = d1;
    }
    __syncthreads();
    if (tid == 0) {
        float logit = dot0 + c1dot + fc_b[0];
        out[b] = 1.f / (1.f + expf(-logit));
    }
}

// ---------------------------------------------------------------------------
extern "C" void kernel_launch(void* const* d_in, const int* in_sizes, int n_in,
                              void* d_out, int out_size, void* d_ws, size_t ws_size,
                              hipStream_t stream)
{
    const int*   x_categ = (const int*)d_in[0];
    const float* x_cont  = (const float*)d_in[1];
    const float* embed   = (const float*)d_in[2];
    const float* ln1_g   = (const float*)d_in[3];
    const float* ln1_b   = (const float*)d_in[4];
    const float* wqkv    = (const float*)d_in[5];
    const float* wo      = (const float*)d_in[6];
    const float* bo      = (const float*)d_in[7];
    const float* ln2_g   = (const float*)d_in[8];
    const float* ln2_b   = (const float*)d_in[9];
    const float* wff1    = (const float*)d_in[10];
    const float* bff1    = (const float*)d_in[11];
    const float* wff2    = (const float*)d_in[12];
    const float* bff2    = (const float*)d_in[13];
    const float* bn_g    = (const float*)d_in[14];
    const float* bn_b    = (const float*)d_in[15];
    const float* g0_w    = (const float*)d_in[16];
    const float* g0_b    = (const float*)d_in[17];
    const float* h0_w    = (const float*)d_in[18];
    const float* y1_w    = (const float*)d_in[19];
    const float* y1_b    = (const float*)d_in[20];
    const float* g1_w    = (const float*)d_in[21];
    const float* g1_b    = (const float*)d_in[22];
    const float* h1_w    = (const float*)d_in[23];
    const float* fc_w    = (const float*)d_in[24];
    const float* fc_b    = (const float*)d_in[25];

    // ---- workspace layout (no aliasing, ~46 MB) ----
    char* ws = (char*)d_ws;
    size_t off = 0;
    auto alloc = [&](size_t bytes) { void* pp = ws + off; off += (bytes + 255) & ~255ULL; return pp; };
    __hip_bfloat16* wqT  = (__hip_bfloat16*)alloc((size_t)DEPTH * 384 * 64 * 2);
    __hip_bfloat16* woT  = (__hip_bfloat16*)alloc((size_t)DEPTH * 64 * 128 * 2);
    __hip_bfloat16* w1T  = (__hip_bfloat16*)alloc((size_t)DEPTH * 512 * 64 * 2);
    __hip_bfloat16* w2T  = (__hip_bfloat16*)alloc((size_t)DEPTH * 64 * 256 * 2);
    __hip_bfloat16* h0T  = (__hip_bfloat16*)alloc((size_t)CATF * 64 * 2);
    __hip_bfloat16* y1T  = (__hip_bfloat16*)alloc((size_t)CATF * 64 * 2);
    __hip_bfloat16* Acat = (__hip_bfloat16*)alloc((size_t)B_ * KTOT * 2);
    __hip_bfloat16* WT   = (__hip_bfloat16*)alloc((size_t)CATF * KTOT * 2);
    __hip_bfloat16* G    = (__hip_bfloat16*)alloc((size_t)B_ * CATF * 2);
    float*          norm = (float*)alloc((size_t)B_ * NCONT * 4);
    float*          y1v  = (float*)alloc((size_t)B_ * NCONT * 4);

    // weight prep
    k_wT<<<576, 256, 0, stream>>>(wqkv, wqT, 64, 384);
    k_wT<<<192, 256, 0, stream>>>(wo,   woT, 128, 64);
    k_wT<<<768, 256, 0, stream>>>(wff1, w1T, 64, 512);
    k_wT<<<384, 256, 0, stream>>>(wff2, w2T, 256, 64);
    k_wT<<<512, 256, 0, stream>>>(h0_w, h0T, 64, 2048);
    k_wT<<<512, 256, 0, stream>>>(y1_w, y1T, 2048, 64);

    // transformer megakernel (emb + 6 layers + cast)
    k_former<<<NROW / 64, 128, 0, stream>>>(x_categ, embed, ln1_g, ln1_b, wqT, woT, bo,
                                            ln2_g, ln2_b, w1T, bff1, w2T, bff2, Acat);

    k_bn<<<NCONT, 256, 0, stream>>>(x_cont, bn_g, bn_b, norm, Acat);
    k_transpose<<<dim3(CATF / 64, KTOT / 64), 256, 0, stream>>>(g0_w, WT);
    k_gemm_g0<<<dim3(CATF / 128, B_ / 128), 256, 0, stream>>>(Acat, WT, g0_b, G);
    k_y1v2<<<B_ / 128, 256, 0, stream>>>(Acat, y1T, y1_b, y1v);
    k_H2<<<dim3(CATF / 128, B_ / 128), 256, 0, stream>>>(Acat, h0T, G);
    k_final<<<B_, 256, 0, stream>>>(Acat, G, norm, y1v, g1_w, g1_b, h1_w, fc_w, fc_b, (float*)d_out);
}